// Round 4
// baseline (409.457 us; speedup 1.0000x reference)
//
#include <hip/hip_runtime.h>

// Focal Tversky loss over (8,10,512,512) fp32 logits, (8,512,512) int32 targets.
// argmax(softmax(x)) == argmax(x) -> no softmax needed. Memory-bound:
// channels 1..9 (75.5 MB) + targets (8.4 MB) ~= 84 MB read once -> ~13.3 us floor.
//
// R2: ballot-based wave histogramming (no atomics in hot path) - neutral, atomics
//     were latency-hidden; kept for the cleaner pipe profile.
// R3: single-node fusion. Last-finishing block (device-scope counter) reduces the
//     27x2048 partials and writes the loss. Counter needs no memset: ws is
//     re-poisoned to 0xAA before every launch, so init is 0xAAAAAAAA; we accept
//     {0xAAAAAAAA, 0} inits so the failure mode is loud (no write), never silent.

#define HW4     65536    // 512*512/4 (float4 groups per plane), = 2^16
#define NBLK    2048     // grid; NBLK*256 threads == total 4-pixel groups
#define POISON  0xAAAAAAAAu

// partial layout (transposed for coalesced reduce): pw[c*NBLK + block]
// c in [0,27): 0..8 TP, 9..17 target count, 18..26 pred count
__global__ __launch_bounds__(256) void ftl_fused(const float* __restrict__ inp,
                                                 const int* __restrict__ tgt,
                                                 unsigned int* __restrict__ pw,
                                                 unsigned int* __restrict__ ctr,
                                                 float* __restrict__ out) {
    __shared__ unsigned int s[4][27];
    __shared__ int lastFlag;
    const int tid  = threadIdx.x;
    const int wave = tid >> 6;
    const int lane = tid & 63;

    const int i  = blockIdx.x * 256 + tid;     // 4-pixel group index
    const int b  = i >> 16;                    // image index
    const int gi = i & (HW4 - 1);              // group within image

    const float4* base = reinterpret_cast<const float4*>(inp)
                       + (((size_t)(b * 10 + 1)) << 16) + gi;  // channel 1

    float4 v = base[0];
    float bv0 = v.x, bv1 = v.y, bv2 = v.z, bv3 = v.w;
    int   bc0 = 1,   bc1 = 1,   bc2 = 1,   bc3 = 1;
#pragma unroll
    for (int c = 2; c <= 9; ++c) {
        float4 w = base[((size_t)(c - 1)) << 16];
        if (w.x > bv0) { bv0 = w.x; bc0 = c; }
        if (w.y > bv1) { bv1 = w.y; bc1 = c; }
        if (w.z > bv2) { bv2 = w.z; bc2 = c; }
        if (w.w > bv3) { bv3 = w.w; bc3 = c; }
    }

    const int4 t = reinterpret_cast<const int4*>(tgt)[i];

    unsigned int cTP[9], cT[9], cP[9];
#pragma unroll
    for (int j = 0; j < 9; ++j) { cTP[j] = 0u; cT[j] = 0u; cP[j] = 0u; }

    const unsigned long long vx = __ballot(t.x != 0);
    const unsigned long long vy = __ballot(t.y != 0);
    const unsigned long long vz = __ballot(t.z != 0);
    const unsigned long long vw = __ballot(t.w != 0);

#pragma unroll
    for (int c = 1; c <= 9; ++c) {
        const int j = c - 1;
        {   const unsigned long long tm = __ballot(t.x == c);
            const unsigned long long pm = __ballot(bc0 == c);
            cT[j]  += (unsigned int)__builtin_popcountll(tm);
            cP[j]  += (unsigned int)__builtin_popcountll(pm & vx);
            cTP[j] += (unsigned int)__builtin_popcountll(tm & pm); }
        {   const unsigned long long tm = __ballot(t.y == c);
            const unsigned long long pm = __ballot(bc1 == c);
            cT[j]  += (unsigned int)__builtin_popcountll(tm);
            cP[j]  += (unsigned int)__builtin_popcountll(pm & vy);
            cTP[j] += (unsigned int)__builtin_popcountll(tm & pm); }
        {   const unsigned long long tm = __ballot(t.z == c);
            const unsigned long long pm = __ballot(bc2 == c);
            cT[j]  += (unsigned int)__builtin_popcountll(tm);
            cP[j]  += (unsigned int)__builtin_popcountll(pm & vz);
            cTP[j] += (unsigned int)__builtin_popcountll(tm & pm); }
        {   const unsigned long long tm = __ballot(t.w == c);
            const unsigned long long pm = __ballot(bc3 == c);
            cT[j]  += (unsigned int)__builtin_popcountll(tm);
            cP[j]  += (unsigned int)__builtin_popcountll(pm & vw);
            cTP[j] += (unsigned int)__builtin_popcountll(tm & pm); }
    }

    if (lane == 0) {
#pragma unroll
        for (int j = 0; j < 9; ++j) {
            s[wave][j]      = cTP[j];
            s[wave][9 + j]  = cT[j];
            s[wave][18 + j] = cP[j];
        }
    }
    __syncthreads();
    if (tid < 27)
        pw[tid * NBLK + blockIdx.x] = s[0][tid] + s[1][tid] + s[2][tid] + s[3][tid];

    // ---- completion detection: last-finishing block does the reduction ----
    __threadfence();                       // release partials device-wide
    if (tid == 0) {
        const unsigned int old = atomicAdd(ctr, 1u);
        lastFlag = (old == POISON + (NBLK - 1)) | (old == (NBLK - 1));
    }
    __syncthreads();
    if (!lastFlag) return;
    __threadfence();                       // acquire all blocks' partials

    // 256 threads sum the 27x2048 partial matrix (coalesced rows from L2)
    unsigned int acc[27];
#pragma unroll
    for (int c = 0; c < 27; ++c) {
        const unsigned int* row = pw + c * NBLK;
        unsigned int sum = 0;
#pragma unroll
        for (int k = 0; k < NBLK / 256; ++k) sum += row[tid + 256 * k];
        acc[c] = sum;
    }
#pragma unroll
    for (int c = 0; c < 27; ++c) {
#pragma unroll
        for (int off = 32; off; off >>= 1) acc[c] += __shfl_down(acc[c], off, 64);
    }
    __syncthreads();                       // s[][] reuse
    if (lane == 0) {
#pragma unroll
        for (int c = 0; c < 27; ++c) s[wave][c] = acc[c];
    }
    __syncthreads();
    if (tid == 0) {
        double loss = 0.0;
#pragma unroll
        for (int c = 0; c < 9; ++c) {
            const double TP = (double)(s[0][c]      + s[1][c]      + s[2][c]      + s[3][c]);
            const double Tc = (double)(s[0][9 + c]  + s[1][9 + c]  + s[2][9 + c]  + s[3][9 + c]);
            const double Pc = (double)(s[0][18 + c] + s[1][18 + c] + s[2][18 + c] + s[3][18 + c]);
            const double FN = Tc - TP;
            const double FP = Pc - TP;
            const double tv = (TP + 1.0) / (TP + 0.7 * FN + 0.3 * FP + 1.0);
            loss += pow(1.0 - tv, 4.0 / 3.0);
        }
        out[0] = (float)loss;
    }
}

extern "C" void kernel_launch(void* const* d_in, const int* in_sizes, int n_in,
                              void* d_out, int out_size, void* d_ws, size_t ws_size,
                              hipStream_t stream) {
    const float* inp = (const float*)d_in[0];
    const int*   tgt = (const int*)d_in[1];
    unsigned int* pw  = (unsigned int*)d_ws;        // 27*NBLK partials, no init needed
    unsigned int* ctr = pw + 27 * NBLK;             // completion counter (poison-init)
    float* out = (float*)d_out;

    ftl_fused<<<dim3(NBLK), dim3(256), 0, stream>>>(inp, tgt, pw, ctr, out);
}

// Round 5
// 159.472 us; speedup vs baseline: 2.5676x; 2.5676x over previous
//
#include <hip/hip_runtime.h>

// Focal Tversky loss over (8,10,512,512) fp32 logits, (8,512,512) int32 targets.
// argmax(softmax(x)) == argmax(x) -> no softmax needed. Memory-bound:
// channels 1..9 (75.5 MB) + targets (8.4 MB) read once -> ~13 us kernel floor.
//
// R2: ballot-based wave histogramming (no hot-path atomics) - kept.
// R4 post-mortem: per-block __threadfence() (device-scope release -> L2
//     writeback on non-coherent per-XCD L2s) x 2048 blocks serialized at the
//     cache fabric: 330 us at 1.6% HBM. Fences removed entirely.
// R5: fence-FREE single-node fusion. All cross-block data moves through
//     device-scope atomicAdd (coherent-point RMW, no flush needed). Ordering:
//     compiler-emitted s_waitcnt vmcnt(0) before s_barrier + explicit
//     consumption of atomic return values, then the completion-counter bump.
//     Counter poison (ws = 0xAA) is subtracted; the completion counter's old
//     value self-detects poison-vs-zero init, so no silent-wrong path.

#define HW4     65536    // 512*512/4 (float4 groups per plane), = 2^16
#define NBLK    2048     // grid; NBLK*256 threads == total 4-pixel groups
#define POISON  0xAAAAAAAAu

// cnt[0..26]: 0..8 TP, 9..17 target count, 18..26 pred count (poison-offset)
// cnt[27]:    completion counter
__global__ __launch_bounds__(256) void ftl_one(const float* __restrict__ inp,
                                               const int* __restrict__ tgt,
                                               unsigned int* __restrict__ cnt,
                                               float* __restrict__ out) {
    __shared__ unsigned int s[4][27];
    __shared__ unsigned int sAdj;
    __shared__ int sLast;
    const int tid  = threadIdx.x;
    const int wave = tid >> 6;
    const int lane = tid & 63;

    const int i  = blockIdx.x * 256 + tid;     // 4-pixel group index
    const int b  = i >> 16;                    // image index
    const int gi = i & (HW4 - 1);              // group within image

    const float4* base = reinterpret_cast<const float4*>(inp)
                       + (((size_t)(b * 10 + 1)) << 16) + gi;  // channel 1

    float4 v = base[0];
    float bv0 = v.x, bv1 = v.y, bv2 = v.z, bv3 = v.w;
    int   bc0 = 1,   bc1 = 1,   bc2 = 1,   bc3 = 1;
#pragma unroll
    for (int c = 2; c <= 9; ++c) {
        float4 w = base[((size_t)(c - 1)) << 16];
        if (w.x > bv0) { bv0 = w.x; bc0 = c; }
        if (w.y > bv1) { bv1 = w.y; bc1 = c; }
        if (w.z > bv2) { bv2 = w.z; bc2 = c; }
        if (w.w > bv3) { bv3 = w.w; bc3 = c; }
    }

    const int4 t = reinterpret_cast<const int4*>(tgt)[i];

    unsigned int cTP[9], cT[9], cP[9];
#pragma unroll
    for (int j = 0; j < 9; ++j) { cTP[j] = 0u; cT[j] = 0u; cP[j] = 0u; }

    const unsigned long long vx = __ballot(t.x != 0);
    const unsigned long long vy = __ballot(t.y != 0);
    const unsigned long long vz = __ballot(t.z != 0);
    const unsigned long long vw = __ballot(t.w != 0);

#pragma unroll
    for (int c = 1; c <= 9; ++c) {
        const int j = c - 1;
        {   const unsigned long long tm = __ballot(t.x == c);
            const unsigned long long pm = __ballot(bc0 == c);
            cT[j]  += (unsigned int)__builtin_popcountll(tm);
            cP[j]  += (unsigned int)__builtin_popcountll(pm & vx);
            cTP[j] += (unsigned int)__builtin_popcountll(tm & pm); }
        {   const unsigned long long tm = __ballot(t.y == c);
            const unsigned long long pm = __ballot(bc1 == c);
            cT[j]  += (unsigned int)__builtin_popcountll(tm);
            cP[j]  += (unsigned int)__builtin_popcountll(pm & vy);
            cTP[j] += (unsigned int)__builtin_popcountll(tm & pm); }
        {   const unsigned long long tm = __ballot(t.z == c);
            const unsigned long long pm = __ballot(bc2 == c);
            cT[j]  += (unsigned int)__builtin_popcountll(tm);
            cP[j]  += (unsigned int)__builtin_popcountll(pm & vz);
            cTP[j] += (unsigned int)__builtin_popcountll(tm & pm); }
        {   const unsigned long long tm = __ballot(t.w == c);
            const unsigned long long pm = __ballot(bc3 == c);
            cT[j]  += (unsigned int)__builtin_popcountll(tm);
            cP[j]  += (unsigned int)__builtin_popcountll(pm & vw);
            cTP[j] += (unsigned int)__builtin_popcountll(tm & pm); }
    }

    if (lane == 0) {
#pragma unroll
        for (int j = 0; j < 9; ++j) {
            s[wave][j]      = cTP[j];
            s[wave][9 + j]  = cT[j];
            s[wave][18 + j] = cP[j];
        }
    }
    __syncthreads();

    // Per-block totals -> device-scope atomics (coherent-point RMW, no fence).
    if (tid < 27) {
        const unsigned int tot = s[0][tid] + s[1][tid] + s[2][tid] + s[3][tid];
        const unsigned int old = atomicAdd(&cnt[tid], tot);
        if (old + 1u == 0u) out[0] = -1.0f;   // consume return value (never true)
    }
    // s_barrier is preceded by compiler-emitted s_waitcnt vmcnt(0):
    // wave 0's counter RMWs have completed at the coherent point here.
    __syncthreads();

    if (tid == 0) {
        const unsigned int old = atomicAdd(&cnt[27], 1u);
        sLast = (old == POISON + (NBLK - 1)) | (old == (NBLK - 1));
        sAdj  = (old == (NBLK - 1)) ? 0u : POISON;   // self-detect ws init
    }
    __syncthreads();
    if (!sLast) return;

    // Last-finishing block: coherent read-back via atomicAdd(p, 0).
    if (tid < 27)
        s[0][tid] = atomicAdd(&cnt[tid], 0u) - sAdj;
    __syncthreads();

    if (tid == 0) {
        double loss = 0.0;
#pragma unroll
        for (int c = 0; c < 9; ++c) {
            const double TP = (double)s[0][c];
            const double FN = (double)s[0][9 + c]  - TP;
            const double FP = (double)s[0][18 + c] - TP;
            const double tv = (TP + 1.0) / (TP + 0.7 * FN + 0.3 * FP + 1.0);
            loss += pow(1.0 - tv, 4.0 / 3.0);
        }
        out[0] = (float)loss;
    }
}

extern "C" void kernel_launch(void* const* d_in, const int* in_sizes, int n_in,
                              void* d_out, int out_size, void* d_ws, size_t ws_size,
                              hipStream_t stream) {
    const float* inp = (const float*)d_in[0];
    const int*   tgt = (const int*)d_in[1];
    unsigned int* cnt = (unsigned int*)d_ws;   // 28 u32: 27 counters + completion ctr
    float* out = (float*)d_out;

    ftl_one<<<dim3(NBLK), dim3(256), 0, stream>>>(inp, tgt, cnt, out);
}

// Round 6
// 131.547 us; speedup vs baseline: 3.1126x; 1.2123x over previous
//
#include <hip/hip_runtime.h>

// Focal Tversky loss over (8,10,512,512) fp32 logits, (8,512,512) int32 targets.
// argmax(softmax(x)) == argmax(x) -> no softmax needed. 84 MB read once.
//
// R2: ballot-based wave histogramming (no hot-path atomics) - kept.
// R4/R5 post-mortem: single-node fusion regressed (threadfence L2-flush storm;
//     then same-line atomic funnel with whole grid resident, no tail hiding).
//     Two-node structure restored.
// R5 key finding: VGPR_Count=28 -> compiler serialized the 9 channel loads
//     (2-3 outstanding) -> latency-bound at 625 GB/s. R6: batch ALL 10 loads
//     into named registers BEFORE any compare -> 10-deep MLP per thread.

#define HW4     65536    // 512*512/4 (float4 groups per plane), = 2^16
#define NBLK    2048     // hist grid; NBLK*256 == total 4-pixel groups

// partial layout (transposed for coalesced reduce): pw[c*NBLK + block]
// c in [0,27): 0..8 TP, 9..17 target count, 18..26 pred count
__global__ __launch_bounds__(256) void ftl_hist(const float* __restrict__ inp,
                                                const int* __restrict__ tgt,
                                                unsigned int* __restrict__ pw) {
    __shared__ unsigned int s[4][27];
    const int tid  = threadIdx.x;
    const int wave = tid >> 6;
    const int lane = tid & 63;

    const int i  = blockIdx.x * 256 + tid;     // 4-pixel group index
    const int b  = i >> 16;                    // image index
    const int gi = i & (HW4 - 1);              // group within image

    const float4* base = reinterpret_cast<const float4*>(inp)
                       + (((size_t)(b * 10 + 1)) << 16) + gi;  // channel 1

    // ---- issue ALL loads first: 9 float4 + 1 int4 in flight per thread ----
    const float4 w0 = base[0];
    const float4 w1 = base[(size_t)1 << 16];
    const float4 w2 = base[(size_t)2 << 16];
    const float4 w3 = base[(size_t)3 << 16];
    const float4 w4 = base[(size_t)4 << 16];
    const float4 w5 = base[(size_t)5 << 16];
    const float4 w6 = base[(size_t)6 << 16];
    const float4 w7 = base[(size_t)7 << 16];
    const float4 w8 = base[(size_t)8 << 16];
    const int4   t  = reinterpret_cast<const int4*>(tgt)[i];

    // ---- argmax over channels 1..9 (compare tree after loads drain) ----
    float bv0 = w0.x, bv1 = w0.y, bv2 = w0.z, bv3 = w0.w;
    int   bc0 = 1,    bc1 = 1,    bc2 = 1,    bc3 = 1;
#define ARGMAX_STEP(W, C) \
    if (W.x > bv0) { bv0 = W.x; bc0 = C; } \
    if (W.y > bv1) { bv1 = W.y; bc1 = C; } \
    if (W.z > bv2) { bv2 = W.z; bc2 = C; } \
    if (W.w > bv3) { bv3 = W.w; bc3 = C; }
    ARGMAX_STEP(w1, 2) ARGMAX_STEP(w2, 3) ARGMAX_STEP(w3, 4) ARGMAX_STEP(w4, 5)
    ARGMAX_STEP(w5, 6) ARGMAX_STEP(w6, 7) ARGMAX_STEP(w7, 8) ARGMAX_STEP(w8, 9)
#undef ARGMAX_STEP

    unsigned int cTP[9], cT[9], cP[9];
#pragma unroll
    for (int j = 0; j < 9; ++j) { cTP[j] = 0u; cT[j] = 0u; cP[j] = 0u; }

    const unsigned long long vx = __ballot(t.x != 0);
    const unsigned long long vy = __ballot(t.y != 0);
    const unsigned long long vz = __ballot(t.z != 0);
    const unsigned long long vw = __ballot(t.w != 0);

#pragma unroll
    for (int c = 1; c <= 9; ++c) {
        const int j = c - 1;
        {   const unsigned long long tm = __ballot(t.x == c);
            const unsigned long long pm = __ballot(bc0 == c);
            cT[j]  += (unsigned int)__builtin_popcountll(tm);
            cP[j]  += (unsigned int)__builtin_popcountll(pm & vx);
            cTP[j] += (unsigned int)__builtin_popcountll(tm & pm); }
        {   const unsigned long long tm = __ballot(t.y == c);
            const unsigned long long pm = __ballot(bc1 == c);
            cT[j]  += (unsigned int)__builtin_popcountll(tm);
            cP[j]  += (unsigned int)__builtin_popcountll(pm & vy);
            cTP[j] += (unsigned int)__builtin_popcountll(tm & pm); }
        {   const unsigned long long tm = __ballot(t.z == c);
            const unsigned long long pm = __ballot(bc2 == c);
            cT[j]  += (unsigned int)__builtin_popcountll(tm);
            cP[j]  += (unsigned int)__builtin_popcountll(pm & vz);
            cTP[j] += (unsigned int)__builtin_popcountll(tm & pm); }
        {   const unsigned long long tm = __ballot(t.w == c);
            const unsigned long long pm = __ballot(bc3 == c);
            cT[j]  += (unsigned int)__builtin_popcountll(tm);
            cP[j]  += (unsigned int)__builtin_popcountll(pm & vw);
            cTP[j] += (unsigned int)__builtin_popcountll(tm & pm); }
    }

    if (lane == 0) {
#pragma unroll
        for (int j = 0; j < 9; ++j) {
            s[wave][j]      = cTP[j];
            s[wave][9 + j]  = cT[j];
            s[wave][18 + j] = cP[j];
        }
    }
    __syncthreads();
    if (tid < 27)
        pw[tid * NBLK + blockIdx.x] = s[0][tid] + s[1][tid] + s[2][tid] + s[3][tid];
}

// One block, 896 threads: 27 groups of 32 lanes each sum one counter row
// (coalesced), shuffle-reduce, thread 0 does the 9-term Tversky sum in double.
__global__ __launch_bounds__(896) void ftl_reduce(const unsigned int* __restrict__ pw,
                                                  float* __restrict__ out) {
    __shared__ double cs[27];
    const int tid = threadIdx.x;
    const int g = tid >> 5;
    const int l = tid & 31;
    if (g < 27) {
        unsigned int sum = 0;
        const unsigned int* row = pw + g * NBLK;
#pragma unroll 8
        for (int k = l; k < NBLK; k += 32) sum += row[k];
#pragma unroll
        for (int off = 16; off; off >>= 1) sum += __shfl_down(sum, off, 32);
        if (l == 0) cs[g] = (double)sum;
    }
    __syncthreads();
    if (tid == 0) {
        double loss = 0.0;
#pragma unroll
        for (int c = 0; c < 9; ++c) {
            const double TP = cs[c];
            const double FN = cs[9 + c]  - TP;
            const double FP = cs[18 + c] - TP;
            const double tv = (TP + 1.0) / (TP + 0.7 * FN + 0.3 * FP + 1.0);
            loss += pow(1.0 - tv, 4.0 / 3.0);
        }
        out[0] = (float)loss;
    }
}

extern "C" void kernel_launch(void* const* d_in, const int* in_sizes, int n_in,
                              void* d_out, int out_size, void* d_ws, size_t ws_size,
                              hipStream_t stream) {
    const float* inp = (const float*)d_in[0];
    const int*   tgt = (const int*)d_in[1];
    unsigned int* pw = (unsigned int*)d_ws;    // 27*NBLK partials, no init needed
    float* out = (float*)d_out;

    ftl_hist<<<dim3(NBLK), dim3(256), 0, stream>>>(inp, tgt, pw);
    ftl_reduce<<<dim3(1), dim3(896), 0, stream>>>(pw, out);
}